// Round 1
// 1260.408 us; speedup vs baseline: 1.0894x; 1.0894x over previous
//
#include <hip/hip_runtime.h>
#include <math.h>

#define CLS 128  // number of classes (C in the reference)

__device__ __forceinline__ float4 fmax4(float4 a, float4 b) {
    a.x = fmaxf(a.x, b.x);
    a.y = fmaxf(a.y, b.y);
    a.z = fmaxf(a.z, b.z);
    a.w = fmaxf(a.w, b.w);
    return a;
}

// ---------------------------------------------------------------------------
// Kernel 1: find segment starts. bag[] is sorted & contiguous (0..M-1, each
// nonempty). starts[m] = first index of bag m; starts[M] = N.
// ---------------------------------------------------------------------------
__global__ __launch_bounds__(256) void find_starts_kernel(
    const int* __restrict__ bag, int* __restrict__ starts, int N, int M) {
    int i = blockIdx.x * blockDim.x + threadIdx.x;
    if (i >= N) return;
    if (i == 0) {
        starts[bag[0]] = 0;
        starts[M] = N;
    } else if (bag[i] != bag[i - 1]) {
        starts[bag[i]] = i;
    }
}

// ---------------------------------------------------------------------------
// Kernel 2: one block (128 threads = 2 waves) per bag.
//
// A bag's data is a CONTIGUOUS run of (e-s)*128 floats = (e-s)*32 float4s.
// Thread t reads flat float4 indices t, t+128, t+256, ...  Since 128*4 is a
// multiple of CLS=128, every float4 thread t touches covers the same class
// group 4*(t%32) .. 4*(t%32)+3, so one running float4-max per accumulator
// suffices.  Two accumulators (k and k+128) give 2 independent 16B loads in
// flight per lane (vs one dependent 4B load before: 8x the bytes in flight).
//
// Reduction: one LDS float4 exchange + ONE __syncthreads to fold the 4
// row-interleaved copies of each class group, then wave-0 shuffles for the
// 128-class logsumexp (replaces 14 __syncthreads of LDS tree reduction).
// ---------------------------------------------------------------------------
__global__ __launch_bounds__(CLS) void bag_loss_kernel(
    const float* __restrict__ input, const int* __restrict__ target,
    const int* __restrict__ starts, float* __restrict__ losses) {
    const int m = blockIdx.x;
    const int t = threadIdx.x;  // 0..127
    const int s = starts[m];
    const int e = starts[m + 1];

    const float4* __restrict__ base = (const float4*)(input + (size_t)s * CLS);
    const int nf4 = (e - s) * (CLS / 4);  // float4s in this bag

    float4 a0 = make_float4(-INFINITY, -INFINITY, -INFINITY, -INFINITY);
    float4 a1 = a0;
    for (int k = t; k < nf4; k += 256) {
        float4 v = base[k];
        const int k2 = k + 128;
        if (k2 < nf4) {
            float4 w = base[k2];
            a1 = fmax4(a1, w);
        }
        a0 = fmax4(a0, v);
    }
    a0 = fmax4(a0, a1);  // running max for classes 4*(t%32) .. +3

    // Fold the 4 copies (threads g, g+32, g+64, g+96 share a class group).
    __shared__ float4 sm[CLS];
    sm[t] = a0;
    __syncthreads();

    if (t < 32) {
        const float4 f = fmax4(fmax4(sm[t], sm[t + 32]),
                               fmax4(sm[t + 64], sm[t + 96]));
        // f = final bag maxima for classes 4t .. 4t+3 (t = 0..31, all wave 0)

        // 128-class max: per-lane max of 4, then xor-butterfly over 32 lanes.
        float lm = fmaxf(fmaxf(f.x, f.y), fmaxf(f.z, f.w));
        #pragma unroll
        for (int mask = 16; mask > 0; mask >>= 1)
            lm = fmaxf(lm, __shfl_xor(lm, mask, 64));

        // sum of exp(x - max)
        float ssum = expf(f.x - lm) + expf(f.y - lm) +
                     expf(f.z - lm) + expf(f.w - lm);
        #pragma unroll
        for (int mask = 16; mask > 0; mask >>= 1)
            ssum += __shfl_xor(ssum, mask, 64);

        // picked = bag max of the target class, via in-wave broadcast
        const int tc = target[m];
        const int src = tc >> 2;
        const int elem = tc & 3;
        float pf = (elem == 0) ? f.x : (elem == 1) ? f.y : (elem == 2) ? f.z : f.w;
        const float picked = __shfl(pf, src, 64);

        if (t == 0) losses[m] = lm + logf(ssum) - picked;
    }
}

// ---------------------------------------------------------------------------
// Kernel 3a/3b: deterministic two-stage mean over M losses.
// ---------------------------------------------------------------------------
__global__ __launch_bounds__(256) void reduce_partial_kernel(
    const float* __restrict__ losses, float* __restrict__ partials, int M) {
    __shared__ float sm[256];
    float s = 0.f;
    for (int i = blockIdx.x * 256 + threadIdx.x; i < M; i += gridDim.x * 256)
        s += losses[i];
    sm[threadIdx.x] = s;
    __syncthreads();
    #pragma unroll
    for (int off = 128; off > 0; off >>= 1) {
        if (threadIdx.x < off) sm[threadIdx.x] += sm[threadIdx.x + off];
        __syncthreads();
    }
    if (threadIdx.x == 0) partials[blockIdx.x] = sm[0];
}

__global__ __launch_bounds__(256) void reduce_final_kernel(
    const float* __restrict__ partials, float* __restrict__ out, float invM) {
    __shared__ float sm[256];
    sm[threadIdx.x] = partials[threadIdx.x];
    __syncthreads();
    #pragma unroll
    for (int off = 128; off > 0; off >>= 1) {
        if (threadIdx.x < off) sm[threadIdx.x] += sm[threadIdx.x + off];
        __syncthreads();
    }
    if (threadIdx.x == 0) out[0] = sm[0] * invM;
}

extern "C" void kernel_launch(void* const* d_in, const int* in_sizes, int n_in,
                              void* d_out, int out_size, void* d_ws, size_t ws_size,
                              hipStream_t stream) {
    const float* input  = (const float*)d_in[0];  // [N, C] f32
    const int*   target = (const int*)d_in[1];    // [M] i32
    const int*   bag    = (const int*)d_in[2];    // [N] i32, sorted contiguous
    const int M = in_sizes[1];
    const int N = in_sizes[2];
    float* out = (float*)d_out;

    // workspace layout: starts[M+1] ints | losses[M] floats | partials[256]
    char* ws = (char*)d_ws;
    int* starts = (int*)ws;
    size_t off = ((size_t)(M + 1) * sizeof(int) + 255) & ~(size_t)255;
    float* losses = (float*)(ws + off);
    off += ((size_t)M * sizeof(float) + 255) & ~(size_t)255;
    float* partials = (float*)(ws + off);

    find_starts_kernel<<<(N + 255) / 256, 256, 0, stream>>>(bag, starts, N, M);
    bag_loss_kernel<<<M, CLS, 0, stream>>>(input, target, starts, losses);
    reduce_partial_kernel<<<256, 256, 0, stream>>>(losses, partials, M);
    reduce_final_kernel<<<1, 256, 0, stream>>>(partials, out, 1.0f / M);
}